// Round 8
// baseline (680.543 us; speedup 1.0000x reference)
//
#include <hip/hip_runtime.h>

// ---------------- types / helpers ----------------
typedef __bf16 bf16x8 __attribute__((ext_vector_type(8)));
typedef float  f32x4  __attribute__((ext_vector_type(4)));

__device__ __forceinline__ f32x4 MFMA(bf16x8 a, bf16x8 b, f32x4 c) {
    return __builtin_amdgcn_mfma_f32_16x16x32_bf16(a, b, c, 0, 0, 0);
}

__device__ __forceinline__ unsigned short f2bfu(float f) {
    unsigned int u = __builtin_bit_cast(unsigned int, f);
    u += 0x7FFFu + ((u >> 16) & 1u);
    return (unsigned short)(u >> 16);
}
__device__ __forceinline__ float bf2f(unsigned short s) {
    unsigned int u = ((unsigned int)s) << 16;
    return __builtin_bit_cast(float, u);
}
__device__ __forceinline__ float sigm(float x) { return 1.f / (1.f + __expf(-x)); }
__device__ __forceinline__ float tanh_f(float x) { return 1.f - 2.f / (__expf(2.f * x) + 1.f); }
// concrete dropout: z = sigmoid((plog + log u - log(1-u))/0.1); out = x*(1-z)/(1-p)
__device__ __forceinline__ float cdrop(float x, float u, float plog, float scale) {
    float t = (plog + __logf(u) - __logf(1.f - u)) * 10.f;
    float z = 1.f / (1.f + __expf(-t));
    return x * (1.f - z) * scale;
}

// ---------------- small kernels ----------------
__global__ void k_zero(float* acc) {
    if (threadIdx.x < 4) acc[threadIdx.x] = 0.f;
}

// Convert 5 weight matrices fp32 -> bf16 with K-padded layouts; accumulate sum(W*W)
__global__ void k_convert(const float* __restrict__ Win, const float* __restrict__ Wih,
                          const float* __restrict__ Whh, const float* __restrict__ Wfc1,
                          const float* __restrict__ Wfc2,
                          unsigned short* __restrict__ WinP, unsigned short* __restrict__ WihP,
                          unsigned short* __restrict__ WhhP, unsigned short* __restrict__ Wfc1P,
                          unsigned short* __restrict__ Wfc2b, float* __restrict__ acc) {
    __shared__ float s3[3];
    int tid = threadIdx.x;
    if (tid < 3) s3[tid] = 0.f;
    __syncthreads();
    int idx = blockIdx.x * 256 + tid;   // total 580608
    float sq = 0.f; int mi = -1;
    if (idx < 15360) {                                    // W_in [240][48] -> [240][64]
        int row = idx >> 6, kp = idx & 63;
        float v = (kp < 48) ? Win[row * 48 + kp] : 0.f;
        WinP[idx] = f2bfu(v);
        if (kp < 48) { sq = v * v; mi = 0; }
    } else if (idx < 15360 + 184320) {                    // W_ih [720][240] -> [720][256]
        int i = idx - 15360;
        int row = i >> 8, kp = i & 255;
        float v = (kp < 240) ? Wih[row * 240 + kp] : 0.f;
        WihP[i] = f2bfu(v);
    } else if (idx < 15360 + 368640) {                    // W_hh
        int i = idx - 15360 - 184320;
        int row = i >> 8, kp = i & 255;
        float v = (kp < 240) ? Whh[row * 240 + kp] : 0.f;
        WhhP[i] = f2bfu(v);
    } else if (idx < 15360 + 368640 + 131072) {           // W_fc1 [512][240] -> [512][256]
        int i = idx - 15360 - 368640;
        int row = i >> 8, kp = i & 255;
        float v = (kp < 240) ? Wfc1[row * 240 + kp] : 0.f;
        Wfc1P[i] = f2bfu(v);
        if (kp < 240) { sq = v * v; mi = 1; }
    } else if (idx < 15360 + 368640 + 131072 + 65536) {   // W_fc2 [128][512]
        int i = idx - 15360 - 368640 - 131072;
        float v = Wfc2[i];
        Wfc2b[i] = f2bfu(v);
        sq = v * v; mi = 2;
    }
    if (mi >= 0) atomicAdd(&s3[mi], sq);
    __syncthreads();
    if (tid < 3) atomicAdd(&acc[tid], s3[tid]);
}

// x_filt_prev_mean[b][m] = mean_s x_ens[s,b,m]
__global__ void k_colmean(const float* __restrict__ x_ens, float* __restrict__ xfpm) {
    int t = blockIdx.x * 256 + threadIdx.x;   // < 32768
    float s = 0.f;
    for (int ss = 0; ss < 32; ++ss) s += x_ens[ss * 32768 + t];
    xfpm[t] = s * (1.f / 32.f);
}

// per-b: x_pred_mean = xfpm @ F^T, innov = y_t - x_pred_mean @ H^T, feat[48]
__global__ void k_feat(const float* __restrict__ xfpm, const float* __restrict__ F_mat,
                       const float* __restrict__ H_mat, const float* __restrict__ y_t,
                       const float* __restrict__ y_prev, const float* __restrict__ xppm,
                       const float* __restrict__ xpdm, float* __restrict__ feat,
                       float* __restrict__ innov) {
    int b = blockIdx.x * 256 + threadIdx.x;
    if (b >= 2048) return;
    float xm[16];
    #pragma unroll
    for (int m = 0; m < 16; ++m) xm[m] = xfpm[b * 16 + m];
    float xpm[16];
    #pragma unroll
    for (int k = 0; k < 16; ++k) {
        float a = 0.f;
        #pragma unroll
        for (int m = 0; m < 16; ++m) a += xm[m] * F_mat[k * 16 + m];
        xpm[k] = a;
    }
    #pragma unroll
    for (int n = 0; n < 8; ++n) {
        float a = 0.f;
        #pragma unroll
        for (int k = 0; k < 16; ++k) a += xpm[k] * H_mat[n * 16 + k];
        float inn = y_t[b * 8 + n] - a;
        innov[b * 8 + n] = inn;
        feat[b * 48 + 16 + n] = inn;
        feat[b * 48 + 40 + n] = y_t[b * 8 + n] - y_prev[b * 8 + n];
    }
    #pragma unroll
    for (int m = 0; m < 16; ++m) {
        feat[b * 48 + m]      = xm[m] - xpdm[b * 16 + m];
        feat[b * 48 + 24 + m] = xm[m] - xppm[b * 16 + m];
    }
}

// ---------------- fully fused DNN + Kalman-update kernel (32 rows/block, 512 thr) ----------------
// Phases: P0 stage -> P1 x1 -> P2 GRU(h_drop in LDS) -> P3 fc1+cdrop(x2 in LDS)
//         -> P4 fc2 + K@innov -> P5 x_pred + write out (coalesced, single write)
// LDS layout (bytes), total 59392 -> 2 blocks/CU (LDS-limited):
//   [    0, 4608) sAin [32][72]   (aliased later by sA5)
//   [ 4608,21504) sA1  [32][264]  (aliased later by sA5)
//   [21504,38400) sA2  [32][264]  (head aliased later by sA5)
//   [38400,55296) sHd  [32][264]
//   [    0,33280) sA5  [32][520]  (phase 3+ only; sAin/sA1/sA2 dead by then)
//   [55296,56320) sInn [256]f32  [56320,57344) sF [256]f32  [57344,59392) sOut [32][16]f32
// launch_bounds: (512, 2) — hipcc treats arg2 as min BLOCKS/CU (CUDA semantics; evidence:
// (512,4) produced VGPR_Count=64 = 512/8 waves -> scratch spills, 134 MB scratch writes).
// 2 blocks/CU = 16 waves = 4 waves/SIMD -> 128-VGPR cap; P2's ~116 live regs fit, no spill.
__global__ __launch_bounds__(512, 2) void k_fused(
    const float* __restrict__ feat, const float* __restrict__ u_in_g,
    const float* __restrict__ h_ens, const float* __restrict__ u_fc1_g,
    const float* __restrict__ u_fc2_g,
    const unsigned short* __restrict__ WinP, const unsigned short* __restrict__ WihP,
    const unsigned short* __restrict__ WhhP, const unsigned short* __restrict__ Wfc1P,
    const unsigned short* __restrict__ Wfc2b,
    const float* __restrict__ b_in, const float* __restrict__ b_ih,
    const float* __restrict__ b_hh, const float* __restrict__ b_fc1,
    const float* __restrict__ b_fc2,
    const float* __restrict__ p_in_l, const float* __restrict__ p_fc1_l,
    const float* __restrict__ p_fc2_l,
    const float* __restrict__ innov_ws, const float* __restrict__ x_ens,
    const float* __restrict__ F_mat, float* __restrict__ out) {

    __shared__ __align__(16) char smem[59392];
    unsigned short* sAin = (unsigned short*)smem;
    unsigned short* sA1  = (unsigned short*)(smem + 4608);
    unsigned short* sA2  = (unsigned short*)(smem + 21504);
    unsigned short* sHd  = (unsigned short*)(smem + 38400);
    unsigned short* sA5  = (unsigned short*)smem;
    float* sInn = (float*)(smem + 55296);
    float* sF   = (float*)(smem + 56320);
    float* sOut = (float*)(smem + 57344);

    int tid = threadIdx.x;
    int lane = tid & 63, wave = tid >> 6;
    int blk = blockIdx.x;
    int r0 = blk * 32;            // flattened ensemble row (s*2048 + b)
    int b0 = (blk & 63) * 32;     // batch row (feat/innov index)
    float plog_in = p_in_l[0];  float sc_in = 1.f / (1.f - sigm(plog_in));
    float plog_f1 = p_fc1_l[0]; float sc_f1 = 1.f / (1.f - sigm(plog_f1));
    float plog_f2 = p_fc2_l[0]; float sc_f2 = 1.f / (1.f - sigm(plog_f2));

    // ---- P0: stage A_in (cdrop), h_ens->bf16, innov, F; zero K-pads ----
    if (tid < 384) {
        int row = tid / 12, k = (tid % 12) * 4;
        float4 f = *(const float4*)(feat + (b0 + row) * 48 + k);
        float4 u = *(const float4*)(u_in_g + (size_t)(r0 + row) * 48 + k);
        ushort4 o;
        o.x = f2bfu(cdrop(f.x, u.x, plog_in, sc_in));
        o.y = f2bfu(cdrop(f.y, u.y, plog_in, sc_in));
        o.z = f2bfu(cdrop(f.z, u.z, plog_in, sc_in));
        o.w = f2bfu(cdrop(f.w, u.w, plog_in, sc_in));
        *(ushort4*)(sAin + row * 72 + k) = o;
    }
    if (tid < 128) {   // zero pad A_in k in [48,64)
        int row = tid / 4, k = 48 + (tid % 4) * 4;
        ushort4 z4 = {0, 0, 0, 0};
        *(ushort4*)(sAin + row * 72 + k) = z4;
    }
    for (int c = tid; c < 1920; c += 512) {
        int row = c / 60, k = (c % 60) * 4;
        float4 h = *(const float4*)(h_ens + (size_t)(r0 + row) * 240 + k);
        ushort4 o;
        o.x = f2bfu(h.x); o.y = f2bfu(h.y); o.z = f2bfu(h.z); o.w = f2bfu(h.w);
        *(ushort4*)(sA2 + row * 264 + k) = o;
    }
    if (tid < 192) {   // zero pads k in [240,264) for sA1, sA2, sHd
        int row = tid / 6, k = 240 + (tid % 6) * 4;
        ushort4 z4 = {0, 0, 0, 0};
        *(ushort4*)(sA2 + row * 264 + k) = z4;
        *(ushort4*)(sA1 + row * 264 + k) = z4;
        *(ushort4*)(sHd + row * 264 + k) = z4;
    }
    if (tid < 64) *(float4*)(sInn + tid * 4) = *(const float4*)(innov_ws + b0 * 8 + tid * 4);
    if (tid >= 64 && tid < 128) {
        int q = tid - 64;
        *(float4*)(sF + q * 4) = *(const float4*)(F_mat + q * 4);
    }
    __syncthreads();

    int ln = lane & 15, qd = lane >> 4;

    // ---- P1: x1 = relu(A_in @ W_in^T + b_in) -> sA1 ----
    for (int t = wave; t < 15; t += 8) {
        int col = t * 16 + ln;
        float bias = b_in[col];
        f32x4 a0 = {0.f, 0.f, 0.f, 0.f}, a1v = {0.f, 0.f, 0.f, 0.f};
        #pragma unroll
        for (int kk = 0; kk < 2; ++kk) {
            bf16x8 b = *(const bf16x8*)(WinP + (size_t)col * 64 + kk * 32 + qd * 8);
            bf16x8 x0 = *(const bf16x8*)(sAin + ln * 72 + kk * 32 + qd * 8);
            bf16x8 x1 = *(const bf16x8*)(sAin + (16 + ln) * 72 + kk * 32 + qd * 8);
            a0 = MFMA(x0, b, a0);
            a1v = MFMA(x1, b, a1v);
        }
        #pragma unroll
        for (int i = 0; i < 4; ++i) {
            int row = qd * 4 + i;
            float v0 = a0[i] + bias;
            float v1 = a1v[i] + bias;
            sA1[row * 264 + col]        = f2bfu(v0 > 0.f ? v0 : 0.f);
            sA1[(16 + row) * 264 + col] = f2bfu(v1 > 0.f ? v1 : 0.f);
        }
    }
    __syncthreads();

    // ---- P2: GRU; u_fc1 prefetched into regs BEFORE the MFMA chain ----
    for (int t = wave; t < 15; t += 8) {
        int j = t * 16 + ln;
        float upf[8];
        #pragma unroll
        for (int ii = 0; ii < 8; ++ii) {
            int row = (ii >> 2) * 16 + qd * 4 + (ii & 3);
            upf[ii] = u_fc1_g[(size_t)(r0 + row) * 240 + j];
        }
        float bir_b = b_ih[j], biz_b = b_ih[240 + j], bin_b = b_ih[480 + j];
        float bhr_b = b_hh[j], bhz_b = b_hh[240 + j], bhn_b = b_hh[480 + j];
        f32x4 air0 = {0,0,0,0}, aiz0 = {0,0,0,0}, ain0 = {0,0,0,0};
        f32x4 ahr0 = {0,0,0,0}, ahz0 = {0,0,0,0}, ahn0 = {0,0,0,0};
        f32x4 air1 = {0,0,0,0}, aiz1 = {0,0,0,0}, ain1 = {0,0,0,0};
        f32x4 ahr1 = {0,0,0,0}, ahz1 = {0,0,0,0}, ahn1 = {0,0,0,0};
        #pragma unroll
        for (int kk = 0; kk < 8; ++kk) {
            int wo = kk * 32 + qd * 8;
            bf16x8 bir = *(const bf16x8*)(WihP + (size_t)j * 256 + wo);
            bf16x8 biz = *(const bf16x8*)(WihP + (size_t)(240 + j) * 256 + wo);
            bf16x8 bin_ = *(const bf16x8*)(WihP + (size_t)(480 + j) * 256 + wo);
            bf16x8 bhr = *(const bf16x8*)(WhhP + (size_t)j * 256 + wo);
            bf16x8 bhz = *(const bf16x8*)(WhhP + (size_t)(240 + j) * 256 + wo);
            bf16x8 bhn = *(const bf16x8*)(WhhP + (size_t)(480 + j) * 256 + wo);
            int ao0 = ln * 264 + wo;
            int ao1 = (16 + ln) * 264 + wo;
            bf16x8 a1_0 = *(const bf16x8*)(sA1 + ao0);
            bf16x8 a2_0 = *(const bf16x8*)(sA2 + ao0);
            bf16x8 a1_1 = *(const bf16x8*)(sA1 + ao1);
            bf16x8 a2_1 = *(const bf16x8*)(sA2 + ao1);
            air0 = MFMA(a1_0, bir, air0);  air1 = MFMA(a1_1, bir, air1);
            aiz0 = MFMA(a1_0, biz, aiz0);  aiz1 = MFMA(a1_1, biz, aiz1);
            ain0 = MFMA(a1_0, bin_, ain0); ain1 = MFMA(a1_1, bin_, ain1);
            ahr0 = MFMA(a2_0, bhr, ahr0);  ahr1 = MFMA(a2_1, bhr, ahr1);
            ahz0 = MFMA(a2_0, bhz, ahz0);  ahz1 = MFMA(a2_1, bhz, ahz1);
            ahn0 = MFMA(a2_0, bhn, ahn0);  ahn1 = MFMA(a2_1, bhn, ahn1);
        }
        auto epi = [&](int sub, f32x4 air, f32x4 aiz, f32x4 ainn, f32x4 ahr, f32x4 ahz, f32x4 ahn) {
            #pragma unroll
            for (int i = 0; i < 4; ++i) {
                int row = sub * 16 + qd * 4 + i;
                float rg = sigm(air[i] + bir_b + ahr[i] + bhr_b);
                float zg = sigm(aiz[i] + biz_b + ahz[i] + bhz_b);
                float ng = tanh_f(ainn[i] + bin_b + rg * (ahn[i] + bhn_b));
                float hp = bf2f(sA2[row * 264 + j]);
                float hn2 = (1.f - zg) * ng + zg * hp;
                float u = upf[sub * 4 + i];
                sHd[row * 264 + j] = f2bfu(cdrop(hn2, u, plog_f1, sc_f1));
            }
        };
        epi(0, air0, aiz0, ain0, ahr0, ahz0, ahn0);
        epi(1, air1, aiz1, ain1, ahr1, ahz1, ahn1);
    }
    __syncthreads();

    // ---- P3: x2 = relu(hd @ W_fc1^T + b); cdrop(u_fc2) -> sA5 (aliases dead bufs) ----
    for (int t = wave; t < 32; t += 8) {
        int col = t * 16 + ln;
        float u0[4], u1[4];
        #pragma unroll
        for (int i = 0; i < 4; ++i) {
            u0[i] = u_fc2_g[(size_t)(r0 + qd * 4 + i) * 512 + col];
            u1[i] = u_fc2_g[(size_t)(r0 + 16 + qd * 4 + i) * 512 + col];
        }
        float bias = b_fc1[col];
        f32x4 a0 = {0.f, 0.f, 0.f, 0.f}, a1v = {0.f, 0.f, 0.f, 0.f};
        #pragma unroll
        for (int kk = 0; kk < 8; ++kk) {
            int wo = kk * 32 + qd * 8;
            bf16x8 b = *(const bf16x8*)(Wfc1P + (size_t)col * 256 + wo);
            bf16x8 x0 = *(const bf16x8*)(sHd + ln * 264 + wo);
            bf16x8 x1 = *(const bf16x8*)(sHd + (16 + ln) * 264 + wo);
            a0 = MFMA(x0, b, a0);
            a1v = MFMA(x1, b, a1v);
        }
        #pragma unroll
        for (int i = 0; i < 4; ++i) {
            int row = qd * 4 + i;
            float v0 = a0[i] + bias; v0 = v0 > 0.f ? v0 : 0.f;
            float v1 = a1v[i] + bias; v1 = v1 > 0.f ? v1 : 0.f;
            sA5[row * 520 + col]        = f2bfu(cdrop(v0, u0[i], plog_f2, sc_f2));
            sA5[(16 + row) * 520 + col] = f2bfu(cdrop(v1, u1[i], plog_f2, sc_f2));
        }
    }
    __syncthreads();

    // ---- P4: K_vec = A5 @ W_fc2^T + b_fc2; K@innov -> sOut ----
    {
        int t = wave;              // 8 waves == 8 col-tiles
        int j = t * 16 + ln;
        float bias = b_fc2[j];
        int n = lane & 7;
        int m = 2 * t + ((lane >> 3) & 1);
        f32x4 a0 = {0.f, 0.f, 0.f, 0.f}, a1v = {0.f, 0.f, 0.f, 0.f};
        #pragma unroll
        for (int kk = 0; kk < 16; ++kk) {
            int wo = kk * 32 + qd * 8;
            bf16x8 b = *(const bf16x8*)(Wfc2b + (size_t)j * 512 + wo);
            bf16x8 x0 = *(const bf16x8*)(sA5 + ln * 520 + wo);
            bf16x8 x1 = *(const bf16x8*)(sA5 + (16 + ln) * 520 + wo);
            a0 = MFMA(x0, b, a0);
            a1v = MFMA(x1, b, a1v);
        }
        auto epi2 = [&](int sub, f32x4 accv) {
            #pragma unroll
            for (int i = 0; i < 4; ++i) {
                int row = sub * 16 + qd * 4 + i;
                float kv = accv[i] + bias;
                float pr = kv * sInn[row * 8 + n];
                pr += __shfl_xor(pr, 1);
                pr += __shfl_xor(pr, 2);
                pr += __shfl_xor(pr, 4);
                if (n == 0) sOut[row * 16 + m] = pr;
            }
        };
        epi2(0, a0);
        epi2(1, a1v);
    }
    __syncthreads();

    // ---- P5: out = x_ens @ F^T + K@innov, coalesced single write ----
    if (tid < 32) {
        int row = tid;
        float x[16];
        #pragma unroll
        for (int q = 0; q < 4; ++q)
            *(float4*)(x + q * 4) = *(const float4*)(x_ens + (size_t)(r0 + row) * 16 + q * 4);
        #pragma unroll
        for (int mq = 0; mq < 4; ++mq) {
            float4 o;
            float* op = (float*)&o;
            #pragma unroll
            for (int mm = 0; mm < 4; ++mm) {
                int m = mq * 4 + mm;
                float a = 0.f;
                #pragma unroll
                for (int k2 = 0; k2 < 16; ++k2) a += sF[m * 16 + k2] * x[k2];
                op[mm] = a + sOut[row * 16 + m];
            }
            *(float4*)(out + (size_t)(r0 + row) * 16 + mq * 4) = o;
        }
    }
}

// ---------------- regularizer ----------------
__global__ void k_reg(const float* __restrict__ acc, const float* __restrict__ pin,
                      const float* __restrict__ pfc1, const float* __restrict__ pfc2,
                      float* __restrict__ out) {
    float fan[3] = {48.f, 240.f, 512.f};
    float pl[3] = {pin[0], pfc1[0], pfc2[0]};
    float reg = 0.f;
    for (int i = 0; i < 3; ++i) {
        float p = 1.f / (1.f + expf(-pl[i]));
        reg += acc[i] / (1.f - p) + fan[i] * (p * logf(p) + (1.f - p) * logf(1.f - p));
    }
    if (threadIdx.x < 32) out[1048576 + threadIdx.x] = reg;
}

// ---------------- launch ----------------
extern "C" void kernel_launch(void* const* d_in, const int* in_sizes, int n_in,
                              void* d_out, int out_size, void* d_ws, size_t ws_size,
                              hipStream_t stream) {
    const float* y_t    = (const float*)d_in[0];
    const float* x_ens  = (const float*)d_in[1];
    const float* xppm   = (const float*)d_in[2];
    const float* xpdm   = (const float*)d_in[3];
    const float* y_prev = (const float*)d_in[4];
    const float* h_ens  = (const float*)d_in[5];
    const float* F_mat  = (const float*)d_in[6];
    const float* H_mat  = (const float*)d_in[7];
    const float* W_in   = (const float*)d_in[8];
    const float* b_in   = (const float*)d_in[9];
    const float* W_ih   = (const float*)d_in[10];
    const float* b_ih   = (const float*)d_in[11];
    const float* W_hh   = (const float*)d_in[12];
    const float* b_hh   = (const float*)d_in[13];
    const float* W_fc1  = (const float*)d_in[14];
    const float* b_fc1  = (const float*)d_in[15];
    const float* W_fc2  = (const float*)d_in[16];
    const float* b_fc2  = (const float*)d_in[17];
    const float* p_in   = (const float*)d_in[18];
    const float* p_fc1  = (const float*)d_in[19];
    const float* p_fc2  = (const float*)d_in[20];
    const float* u_in   = (const float*)d_in[21];
    const float* u_fc1  = (const float*)d_in[22];
    const float* u_fc2  = (const float*)d_in[23];

    char* ws = (char*)d_ws;
    float* acc            = (float*)(ws + 0);
    unsigned short* WinP  = (unsigned short*)(ws + 64);
    unsigned short* WihP  = (unsigned short*)(ws + 30784);
    unsigned short* WhhP  = (unsigned short*)(ws + 399424);
    unsigned short* Wfc1P = (unsigned short*)(ws + 768064);
    unsigned short* Wfc2b = (unsigned short*)(ws + 1030208);
    float* xfpm           = (float*)(ws + 1161280);
    float* feat           = (float*)(ws + 1292352);
    float* innov          = (float*)(ws + 1685568);
    float* out = (float*)d_out;

    k_zero<<<1, 64, 0, stream>>>(acc);
    k_convert<<<2268, 256, 0, stream>>>(W_in, W_ih, W_hh, W_fc1, W_fc2,
                                        WinP, WihP, WhhP, Wfc1P, Wfc2b, acc);
    k_colmean<<<128, 256, 0, stream>>>(x_ens, xfpm);
    k_feat<<<8, 256, 0, stream>>>(xfpm, F_mat, H_mat, y_t, y_prev, xppm, xpdm, feat, innov);
    k_fused<<<2048, 512, 0, stream>>>(feat, u_in, h_ens, u_fc1, u_fc2,
                                      WinP, WihP, WhhP, Wfc1P, Wfc2b,
                                      b_in, b_ih, b_hh, b_fc1, b_fc2,
                                      p_in, p_fc1, p_fc2, innov, x_ens, F_mat, out);
    k_reg<<<1, 64, 0, stream>>>(acc, p_in, p_fc1, p_fc2, out);
}

// Round 9
// 491.004 us; speedup vs baseline: 1.3860x; 1.3860x over previous
//
#include <hip/hip_runtime.h>

// ---------------- types / helpers ----------------
typedef __bf16 bf16x8 __attribute__((ext_vector_type(8)));
typedef float  f32x4  __attribute__((ext_vector_type(4)));

__device__ __forceinline__ f32x4 MFMA(bf16x8 a, bf16x8 b, f32x4 c) {
    return __builtin_amdgcn_mfma_f32_16x16x32_bf16(a, b, c, 0, 0, 0);
}

__device__ __forceinline__ unsigned short f2bfu(float f) {
    unsigned int u = __builtin_bit_cast(unsigned int, f);
    u += 0x7FFFu + ((u >> 16) & 1u);
    return (unsigned short)(u >> 16);
}
__device__ __forceinline__ float bf2f(unsigned short s) {
    unsigned int u = ((unsigned int)s) << 16;
    return __builtin_bit_cast(float, u);
}
__device__ __forceinline__ float sigm(float x) { return 1.f / (1.f + __expf(-x)); }
__device__ __forceinline__ float tanh_f(float x) { return 1.f - 2.f / (__expf(2.f * x) + 1.f); }
// concrete dropout: z = sigmoid((plog + log u - log(1-u))/0.1); out = x*(1-z)/(1-p)
__device__ __forceinline__ float cdrop(float x, float u, float plog, float scale) {
    float t = (plog + __logf(u) - __logf(1.f - u)) * 10.f;
    float z = 1.f / (1.f + __expf(-t));
    return x * (1.f - z) * scale;
}

// ---------------- small kernels ----------------
__global__ void k_zero(float* acc) {
    if (threadIdx.x < 4) acc[threadIdx.x] = 0.f;
}

// Convert 5 weight matrices fp32 -> bf16 in MFMA-FRAGMENT order; accumulate sum(W*W).
// Fragment layout per matrix: frag[t][kk][lane][8] where lane = qd*16+ln holds
// W[t*16+ln][kk*32+qd*8 .. +7]. A wave's B-fragment load is then ONE contiguous
// 1 KB global_load (was: 16 cache lines at 512 B stride). One thread = one fragment.
// Fragment ranges: WinP 1920 | WihP 23040 | WhhP 23040 | Wfc1P 16384 | Wfc2b 8192
// (total 72576). All K-pads are whole fragments (Kreal multiples of 8).
__global__ void k_convert(const float* __restrict__ Win, const float* __restrict__ Wih,
                          const float* __restrict__ Whh, const float* __restrict__ Wfc1,
                          const float* __restrict__ Wfc2,
                          unsigned short* __restrict__ WinP, unsigned short* __restrict__ WihP,
                          unsigned short* __restrict__ WhhP, unsigned short* __restrict__ Wfc1P,
                          unsigned short* __restrict__ Wfc2b, float* __restrict__ acc) {
    __shared__ float s3[3];
    int tid = threadIdx.x;
    if (tid < 3) s3[tid] = 0.f;
    __syncthreads();
    int f = blockIdx.x * 256 + tid;   // fragment id, total 72576
    float sq = 0.f; int mi = -1;
    if (f < 72576) {
        const float* src; unsigned short* dst;
        int row, wo, kreal, scols, didx;
        if (f < 1920) {                              // W_in [240][48->64], 128 frags/t
            int t = f >> 7, r = f & 127;
            int kk = r >> 6, qd = (r >> 4) & 3, ln = r & 15;
            row = t * 16 + ln; wo = kk * 32 + qd * 8;
            kreal = 48; scols = 48; src = Win; dst = WinP; didx = f * 8;
            if (wo < 48) mi = 0;
        } else if (f < 24960) {                      // W_ih [720][240->256], 512 frags/t'
            int i = f - 1920;
            int tp = i >> 9, r = i & 511;
            int kk = r >> 6, qd = (r >> 4) & 3, ln = r & 15;
            row = (tp / 15) * 240 + (tp % 15) * 16 + ln; wo = kk * 32 + qd * 8;
            kreal = 240; scols = 240; src = Wih; dst = WihP; didx = i * 8;
        } else if (f < 48000) {                      // W_hh
            int i = f - 24960;
            int tp = i >> 9, r = i & 511;
            int kk = r >> 6, qd = (r >> 4) & 3, ln = r & 15;
            row = (tp / 15) * 240 + (tp % 15) * 16 + ln; wo = kk * 32 + qd * 8;
            kreal = 240; scols = 240; src = Whh; dst = WhhP; didx = i * 8;
        } else if (f < 64384) {                      // W_fc1 [512][240->256]
            int i = f - 48000;
            int t = i >> 9, r = i & 511;
            int kk = r >> 6, qd = (r >> 4) & 3, ln = r & 15;
            row = t * 16 + ln; wo = kk * 32 + qd * 8;
            kreal = 240; scols = 240; src = Wfc1; dst = Wfc1P; didx = i * 8;
            if (wo < 240) mi = 1;
        } else {                                     // W_fc2 [128][512], no pad
            int i = f - 64384;
            int t = i >> 10, r = i & 1023;
            int kk = r >> 6, qd = (r >> 4) & 3, ln = r & 15;
            row = t * 16 + ln; wo = kk * 32 + qd * 8;
            kreal = 512; scols = 512; src = Wfc2; dst = Wfc2b; didx = i * 8;
            mi = 2;
        }
        ushort4 o0 = {0, 0, 0, 0}, o1 = {0, 0, 0, 0};
        if (wo < kreal) {
            float4 v0 = *(const float4*)(src + (size_t)row * scols + wo);
            float4 v1 = *(const float4*)(src + (size_t)row * scols + wo + 4);
            o0.x = f2bfu(v0.x); o0.y = f2bfu(v0.y); o0.z = f2bfu(v0.z); o0.w = f2bfu(v0.w);
            o1.x = f2bfu(v1.x); o1.y = f2bfu(v1.y); o1.z = f2bfu(v1.z); o1.w = f2bfu(v1.w);
            sq = v0.x * v0.x + v0.y * v0.y + v0.z * v0.z + v0.w * v0.w
               + v1.x * v1.x + v1.y * v1.y + v1.z * v1.z + v1.w * v1.w;
        }
        *(ushort4*)(dst + didx) = o0;
        *(ushort4*)(dst + didx + 4) = o1;
    }
    if (mi >= 0) atomicAdd(&s3[mi], sq);
    __syncthreads();
    if (tid < 3) atomicAdd(&acc[tid], s3[tid]);
}

// x_filt_prev_mean[b][m] = mean_s x_ens[s,b,m]
__global__ void k_colmean(const float* __restrict__ x_ens, float* __restrict__ xfpm) {
    int t = blockIdx.x * 256 + threadIdx.x;   // < 32768
    float s = 0.f;
    for (int ss = 0; ss < 32; ++ss) s += x_ens[ss * 32768 + t];
    xfpm[t] = s * (1.f / 32.f);
}

// per-b: x_pred_mean = xfpm @ F^T, innov = y_t - x_pred_mean @ H^T, feat[48]
__global__ void k_feat(const float* __restrict__ xfpm, const float* __restrict__ F_mat,
                       const float* __restrict__ H_mat, const float* __restrict__ y_t,
                       const float* __restrict__ y_prev, const float* __restrict__ xppm,
                       const float* __restrict__ xpdm, float* __restrict__ feat,
                       float* __restrict__ innov) {
    int b = blockIdx.x * 256 + threadIdx.x;
    if (b >= 2048) return;
    float xm[16];
    #pragma unroll
    for (int m = 0; m < 16; ++m) xm[m] = xfpm[b * 16 + m];
    float xpm[16];
    #pragma unroll
    for (int k = 0; k < 16; ++k) {
        float a = 0.f;
        #pragma unroll
        for (int m = 0; m < 16; ++m) a += xm[m] * F_mat[k * 16 + m];
        xpm[k] = a;
    }
    #pragma unroll
    for (int n = 0; n < 8; ++n) {
        float a = 0.f;
        #pragma unroll
        for (int k = 0; k < 16; ++k) a += xpm[k] * H_mat[n * 16 + k];
        float inn = y_t[b * 8 + n] - a;
        innov[b * 8 + n] = inn;
        feat[b * 48 + 16 + n] = inn;
        feat[b * 48 + 40 + n] = y_t[b * 8 + n] - y_prev[b * 8 + n];
    }
    #pragma unroll
    for (int m = 0; m < 16; ++m) {
        feat[b * 48 + m]      = xm[m] - xpdm[b * 16 + m];
        feat[b * 48 + 24 + m] = xm[m] - xppm[b * 16 + m];
    }
}

// ---------------- fully fused DNN + Kalman-update kernel (32 rows/block, 512 thr) ----------------
// Register plan (fix for Rd8's 23% occupancy = 1 block/CU): gfx950 unified VGPR+AGPR
// file — Rd8 had 104 VGPR + ~64 AGPR (12 f32x4 acc) = ~168/wave -> 3 waves/SIMD -> 1 block.
// P2 now iterates 30 (t,sub) units with only 6 accumulators (24 AGPR); target total
// <= 128/wave -> 4 waves/SIMD -> 2 blocks/CU (LDS 59392 B allows exactly 2).
// Weight loads use the fragment-ordered layout from k_convert: one coalesced 1 KB
// load per B-fragment (was 16-line scatter) -> TA/L1 transaction work cut ~4-16x.
__global__ __launch_bounds__(512, 2) void k_fused(
    const float* __restrict__ feat, const float* __restrict__ u_in_g,
    const float* __restrict__ h_ens, const float* __restrict__ u_fc1_g,
    const float* __restrict__ u_fc2_g,
    const unsigned short* __restrict__ WinP, const unsigned short* __restrict__ WihP,
    const unsigned short* __restrict__ WhhP, const unsigned short* __restrict__ Wfc1P,
    const unsigned short* __restrict__ Wfc2b,
    const float* __restrict__ b_in, const float* __restrict__ b_ih,
    const float* __restrict__ b_hh, const float* __restrict__ b_fc1,
    const float* __restrict__ b_fc2,
    const float* __restrict__ p_in_l, const float* __restrict__ p_fc1_l,
    const float* __restrict__ p_fc2_l,
    const float* __restrict__ innov_ws, const float* __restrict__ x_ens,
    const float* __restrict__ F_mat, float* __restrict__ out) {

    __shared__ __align__(16) char smem[59392];
    unsigned short* sAin = (unsigned short*)smem;
    unsigned short* sA1  = (unsigned short*)(smem + 4608);
    unsigned short* sA2  = (unsigned short*)(smem + 21504);
    unsigned short* sHd  = (unsigned short*)(smem + 38400);
    unsigned short* sA5  = (unsigned short*)smem;
    float* sInn = (float*)(smem + 55296);
    float* sF   = (float*)(smem + 56320);
    float* sOut = (float*)(smem + 57344);

    int tid = threadIdx.x;
    int lane = tid & 63, wave = tid >> 6;
    int blk = blockIdx.x;
    int r0 = blk * 32;            // flattened ensemble row (s*2048 + b)
    int b0 = (blk & 63) * 32;     // batch row (feat/innov index)
    float plog_in = p_in_l[0];  float sc_in = 1.f / (1.f - sigm(plog_in));
    float plog_f1 = p_fc1_l[0]; float sc_f1 = 1.f / (1.f - sigm(plog_f1));
    float plog_f2 = p_fc2_l[0]; float sc_f2 = 1.f / (1.f - sigm(plog_f2));

    // ---- P0: stage A_in (cdrop), h_ens->bf16, innov, F; zero K-pads ----
    if (tid < 384) {
        int row = tid / 12, k = (tid % 12) * 4;
        float4 f = *(const float4*)(feat + (b0 + row) * 48 + k);
        float4 u = *(const float4*)(u_in_g + (size_t)(r0 + row) * 48 + k);
        ushort4 o;
        o.x = f2bfu(cdrop(f.x, u.x, plog_in, sc_in));
        o.y = f2bfu(cdrop(f.y, u.y, plog_in, sc_in));
        o.z = f2bfu(cdrop(f.z, u.z, plog_in, sc_in));
        o.w = f2bfu(cdrop(f.w, u.w, plog_in, sc_in));
        *(ushort4*)(sAin + row * 72 + k) = o;
    }
    if (tid < 128) {   // zero pad A_in k in [48,64)
        int row = tid / 4, k = 48 + (tid % 4) * 4;
        ushort4 z4 = {0, 0, 0, 0};
        *(ushort4*)(sAin + row * 72 + k) = z4;
    }
    for (int c = tid; c < 1920; c += 512) {
        int row = c / 60, k = (c % 60) * 4;
        float4 h = *(const float4*)(h_ens + (size_t)(r0 + row) * 240 + k);
        ushort4 o;
        o.x = f2bfu(h.x); o.y = f2bfu(h.y); o.z = f2bfu(h.z); o.w = f2bfu(h.w);
        *(ushort4*)(sA2 + row * 264 + k) = o;
    }
    if (tid < 192) {   // zero pads k in [240,264) for sA1, sA2, sHd
        int row = tid / 6, k = 240 + (tid % 6) * 4;
        ushort4 z4 = {0, 0, 0, 0};
        *(ushort4*)(sA2 + row * 264 + k) = z4;
        *(ushort4*)(sA1 + row * 264 + k) = z4;
        *(ushort4*)(sHd + row * 264 + k) = z4;
    }
    if (tid < 64) *(float4*)(sInn + tid * 4) = *(const float4*)(innov_ws + b0 * 8 + tid * 4);
    if (tid >= 64 && tid < 128) {
        int q = tid - 64;
        *(float4*)(sF + q * 4) = *(const float4*)(F_mat + q * 4);
    }
    __syncthreads();

    int ln = lane & 15, qd = lane >> 4;

    // ---- P1: x1 = relu(A_in @ W_in^T + b_in) -> sA1 (fragment-ordered WinP) ----
    for (int t = wave; t < 15; t += 8) {
        int col = t * 16 + ln;
        float bias = b_in[col];
        f32x4 a0 = {0.f, 0.f, 0.f, 0.f}, a1v = {0.f, 0.f, 0.f, 0.f};
        #pragma unroll
        for (int kk = 0; kk < 2; ++kk) {
            bf16x8 b = *(const bf16x8*)(WinP + ((t * 2 + kk) * 64 + lane) * 8);
            bf16x8 x0 = *(const bf16x8*)(sAin + ln * 72 + kk * 32 + qd * 8);
            bf16x8 x1 = *(const bf16x8*)(sAin + (16 + ln) * 72 + kk * 32 + qd * 8);
            a0 = MFMA(x0, b, a0);
            a1v = MFMA(x1, b, a1v);
        }
        #pragma unroll
        for (int i = 0; i < 4; ++i) {
            int row = qd * 4 + i;
            float v0 = a0[i] + bias;
            float v1 = a1v[i] + bias;
            sA1[row * 264 + col]        = f2bfu(v0 > 0.f ? v0 : 0.f);
            sA1[(16 + row) * 264 + col] = f2bfu(v1 > 0.f ? v1 : 0.f);
        }
    }
    __syncthreads();

    // ---- P2: GRU over 30 (t,sub) units; 6 accumulators only (24 AGPR) ----
    // Gate g base offset in fragment layout: g * 61440 ushorts (15 t x 512 frags x 8).
    for (int u = wave; u < 30; u += 8) {
        int t = u >> 1, sub = u & 1;
        int j = t * 16 + ln;
        float upf[4];
        #pragma unroll
        for (int i = 0; i < 4; ++i) {
            int row = sub * 16 + qd * 4 + i;
            upf[i] = u_fc1_g[(size_t)(r0 + row) * 240 + j];
        }
        float bir_b = b_ih[j], biz_b = b_ih[240 + j], bin_b = b_ih[480 + j];
        float bhr_b = b_hh[j], bhz_b = b_hh[240 + j], bhn_b = b_hh[480 + j];
        f32x4 air = {0,0,0,0}, aiz = {0,0,0,0}, ain = {0,0,0,0};
        f32x4 ahr = {0,0,0,0}, ahz = {0,0,0,0}, ahn = {0,0,0,0};
        #pragma unroll
        for (int kk = 0; kk < 8; ++kk) {
            int wb = ((t * 8 + kk) * 64 + lane) * 8;
            bf16x8 bir = *(const bf16x8*)(WihP + wb);
            bf16x8 biz = *(const bf16x8*)(WihP + 61440 + wb);
            bf16x8 bin_ = *(const bf16x8*)(WihP + 122880 + wb);
            bf16x8 bhr = *(const bf16x8*)(WhhP + wb);
            bf16x8 bhz = *(const bf16x8*)(WhhP + 61440 + wb);
            bf16x8 bhn = *(const bf16x8*)(WhhP + 122880 + wb);
            int ao = (sub * 16 + ln) * 264 + kk * 32 + qd * 8;
            bf16x8 a1f = *(const bf16x8*)(sA1 + ao);
            bf16x8 a2f = *(const bf16x8*)(sA2 + ao);
            air = MFMA(a1f, bir, air);
            aiz = MFMA(a1f, biz, aiz);
            ain = MFMA(a1f, bin_, ain);
            ahr = MFMA(a2f, bhr, ahr);
            ahz = MFMA(a2f, bhz, ahz);
            ahn = MFMA(a2f, bhn, ahn);
        }
        #pragma unroll
        for (int i = 0; i < 4; ++i) {
            int row = sub * 16 + qd * 4 + i;
            float rg = sigm(air[i] + bir_b + ahr[i] + bhr_b);
            float zg = sigm(aiz[i] + biz_b + ahz[i] + bhz_b);
            float ng = tanh_f(ain[i] + bin_b + rg * (ahn[i] + bhn_b));
            float hp = bf2f(sA2[row * 264 + j]);
            float hn2 = (1.f - zg) * ng + zg * hp;
            sHd[row * 264 + j] = f2bfu(cdrop(hn2, upf[i], plog_f1, sc_f1));
        }
    }
    __syncthreads();

    // ---- P3: x2 = relu(hd @ W_fc1^T + b); cdrop(u_fc2) -> sA5 (aliases dead bufs) ----
    for (int t = wave; t < 32; t += 8) {
        int col = t * 16 + ln;
        float u0[4], u1[4];
        #pragma unroll
        for (int i = 0; i < 4; ++i) {
            u0[i] = u_fc2_g[(size_t)(r0 + qd * 4 + i) * 512 + col];
            u1[i] = u_fc2_g[(size_t)(r0 + 16 + qd * 4 + i) * 512 + col];
        }
        float bias = b_fc1[col];
        f32x4 a0 = {0.f, 0.f, 0.f, 0.f}, a1v = {0.f, 0.f, 0.f, 0.f};
        #pragma unroll
        for (int kk = 0; kk < 8; ++kk) {
            bf16x8 b = *(const bf16x8*)(Wfc1P + ((t * 8 + kk) * 64 + lane) * 8);
            int ao = ln * 264 + kk * 32 + qd * 8;
            bf16x8 x0 = *(const bf16x8*)(sHd + ao);
            bf16x8 x1 = *(const bf16x8*)(sHd + 16 * 264 + ao);
            a0 = MFMA(x0, b, a0);
            a1v = MFMA(x1, b, a1v);
        }
        #pragma unroll
        for (int i = 0; i < 4; ++i) {
            int row = qd * 4 + i;
            float v0 = a0[i] + bias; v0 = v0 > 0.f ? v0 : 0.f;
            float v1 = a1v[i] + bias; v1 = v1 > 0.f ? v1 : 0.f;
            sA5[row * 520 + col]        = f2bfu(cdrop(v0, u0[i], plog_f2, sc_f2));
            sA5[(16 + row) * 520 + col] = f2bfu(cdrop(v1, u1[i], plog_f2, sc_f2));
        }
    }
    __syncthreads();

    // ---- P4: K_vec = A5 @ W_fc2^T + b_fc2; K@innov -> sOut ----
    {
        int t = wave;              // 8 waves == 8 col-tiles
        int j = t * 16 + ln;
        float bias = b_fc2[j];
        int n = lane & 7;
        int m = 2 * t + ((lane >> 3) & 1);
        f32x4 a0 = {0.f, 0.f, 0.f, 0.f}, a1v = {0.f, 0.f, 0.f, 0.f};
        #pragma unroll
        for (int kk = 0; kk < 16; ++kk) {
            bf16x8 b = *(const bf16x8*)(Wfc2b + ((t * 16 + kk) * 64 + lane) * 8);
            int ao = ln * 520 + kk * 32 + qd * 8;
            bf16x8 x0 = *(const bf16x8*)(sA5 + ao);
            bf16x8 x1 = *(const bf16x8*)(sA5 + 16 * 520 + ao);
            a0 = MFMA(x0, b, a0);
            a1v = MFMA(x1, b, a1v);
        }
        auto epi2 = [&](int sub, f32x4 accv) {
            #pragma unroll
            for (int i = 0; i < 4; ++i) {
                int row = sub * 16 + qd * 4 + i;
                float kv = accv[i] + bias;
                float pr = kv * sInn[row * 8 + n];
                pr += __shfl_xor(pr, 1);
                pr += __shfl_xor(pr, 2);
                pr += __shfl_xor(pr, 4);
                if (n == 0) sOut[row * 16 + m] = pr;
            }
        };
        epi2(0, a0);
        epi2(1, a1v);
    }
    __syncthreads();

    // ---- P5: out = x_ens @ F^T + K@innov, coalesced single write ----
    if (tid < 32) {
        int row = tid;
        float x[16];
        #pragma unroll
        for (int q = 0; q < 4; ++q)
            *(float4*)(x + q * 4) = *(const float4*)(x_ens + (size_t)(r0 + row) * 16 + q * 4);
        #pragma unroll
        for (int mq = 0; mq < 4; ++mq) {
            float4 o;
            float* op = (float*)&o;
            #pragma unroll
            for (int mm = 0; mm < 4; ++mm) {
                int m = mq * 4 + mm;
                float a = 0.f;
                #pragma unroll
                for (int k2 = 0; k2 < 16; ++k2) a += sF[m * 16 + k2] * x[k2];
                op[mm] = a + sOut[row * 16 + m];
            }
            *(float4*)(out + (size_t)(r0 + row) * 16 + mq * 4) = o;
        }
    }
}

// ---------------- regularizer ----------------
__global__ void k_reg(const float* __restrict__ acc, const float* __restrict__ pin,
                      const float* __restrict__ pfc1, const float* __restrict__ pfc2,
                      float* __restrict__ out) {
    float fan[3] = {48.f, 240.f, 512.f};
    float pl[3] = {pin[0], pfc1[0], pfc2[0]};
    float reg = 0.f;
    for (int i = 0; i < 3; ++i) {
        float p = 1.f / (1.f + expf(-pl[i]));
        reg += acc[i] / (1.f - p) + fan[i] * (p * logf(p) + (1.f - p) * logf(1.f - p));
    }
    if (threadIdx.x < 32) out[1048576 + threadIdx.x] = reg;
}

// ---------------- launch ----------------
extern "C" void kernel_launch(void* const* d_in, const int* in_sizes, int n_in,
                              void* d_out, int out_size, void* d_ws, size_t ws_size,
                              hipStream_t stream) {
    const float* y_t    = (const float*)d_in[0];
    const float* x_ens  = (const float*)d_in[1];
    const float* xppm   = (const float*)d_in[2];
    const float* xpdm   = (const float*)d_in[3];
    const float* y_prev = (const float*)d_in[4];
    const float* h_ens  = (const float*)d_in[5];
    const float* F_mat  = (const float*)d_in[6];
    const float* H_mat  = (const float*)d_in[7];
    const float* W_in   = (const float*)d_in[8];
    const float* b_in   = (const float*)d_in[9];
    const float* W_ih   = (const float*)d_in[10];
    const float* b_ih   = (const float*)d_in[11];
    const float* W_hh   = (const float*)d_in[12];
    const float* b_hh   = (const float*)d_in[13];
    const float* W_fc1  = (const float*)d_in[14];
    const float* b_fc1  = (const float*)d_in[15];
    const float* W_fc2  = (const float*)d_in[16];
    const float* b_fc2  = (const float*)d_in[17];
    const float* p_in   = (const float*)d_in[18];
    const float* p_fc1  = (const float*)d_in[19];
    const float* p_fc2  = (const float*)d_in[20];
    const float* u_in   = (const float*)d_in[21];
    const float* u_fc1  = (const float*)d_in[22];
    const float* u_fc2  = (const float*)d_in[23];

    char* ws = (char*)d_ws;
    float* acc            = (float*)(ws + 0);
    unsigned short* WinP  = (unsigned short*)(ws + 64);
    unsigned short* WihP  = (unsigned short*)(ws + 30784);
    unsigned short* WhhP  = (unsigned short*)(ws + 399424);
    unsigned short* Wfc1P = (unsigned short*)(ws + 768064);
    unsigned short* Wfc2b = (unsigned short*)(ws + 1030208);
    float* xfpm           = (float*)(ws + 1161280);
    float* feat           = (float*)(ws + 1292352);
    float* innov          = (float*)(ws + 1685568);
    float* out = (float*)d_out;

    k_zero<<<1, 64, 0, stream>>>(acc);
    k_convert<<<284, 256, 0, stream>>>(W_in, W_ih, W_hh, W_fc1, W_fc2,
                                       WinP, WihP, WhhP, Wfc1P, Wfc2b, acc);
    k_colmean<<<128, 256, 0, stream>>>(x_ens, xfpm);
    k_feat<<<8, 256, 0, stream>>>(xfpm, F_mat, H_mat, y_t, y_prev, xppm, xpdm, feat, innov);
    k_fused<<<2048, 512, 0, stream>>>(feat, u_in, h_ens, u_fc1, u_fc2,
                                      WinP, WihP, WhhP, Wfc1P, Wfc2b,
                                      b_in, b_ih, b_hh, b_fc1, b_fc2,
                                      p_in, p_fc1, p_fc2, innov, x_ens, F_mat, out);
    k_reg<<<1, 64, 0, stream>>>(acc, p_in, p_fc1, p_fc2, out);
}